// Round 13
// baseline (96.891 us; speedup 1.0000x reference)
//
#include <hip/hip_runtime.h>
#include <hip/hip_bf16.h>

typedef __bf16 bf16x8 __attribute__((ext_vector_type(8)));
typedef float  f32x4  __attribute__((ext_vector_type(4)));

constexpr int kNHRZ = 2048, kBATCH = 128, kNU = 64, kNY = 64, kNH = 256, kH = 128;
constexpr int kCHUNK = 256, kNCHUNK = kNHRZ / kCHUNK;  // 8 chunks of 256 steps
constexpr int kTS = 16, kBT = 2, kM = kTS * kBT;       // 32 (t,b) rows per subtile
constexpr int kNSUB = kCHUNK / kTS;                    // 16 subtiles per chunk

// LDS strides (elements)
constexpr int U_STR  = 72;   // bf16, 144 B rows
constexpr int BU_STR = 260;  // bf16, 520 B rows. GEMM1 stores: rows lg*4+i ->
                             // 4*520 = 2080 ≡ 32 (mod 128) -> lg groups on
                             // DISJOINT bank octets (R12's 272 was 4-way).
constexpr int X_STR  = 264;  // bf16, 528 B rows (scan writes 2-way = free)

constexpr int OFF_U  = 0;                            // Us dbuf: 2*32*72*2  = 9216
constexpr int OFF_BU = OFF_U + 2 * kM * U_STR * 2;   // Bu dbuf: 2*32*260*2 = 33280
constexpr int OFF_X  = OFF_BU + 2 * kM * BU_STR * 2; // 42496
constexpr int SMEM1  = OFF_X;                        // pass1: 42496 B -> 3 blk/CU
constexpr int SMEM2  = OFF_X + kM * X_STR * 2;       // pass2: 59392 B -> 2 blk/CU

__device__ inline bf16x8 pack8(float4 a, float4 b) {
    bf16x8 v;
    v[0] = (__bf16)a.x; v[1] = (__bf16)a.y; v[2] = (__bf16)a.z; v[3] = (__bf16)a.w;
    v[4] = (__bf16)b.x; v[5] = (__bf16)b.y; v[6] = (__bf16)b.z; v[7] = (__bf16)b.w;
    return v;
}

// ---------------------------------------------------------------------------
// Software-pipelined fused per-chunk kernel (R12 body, overlapped schedule).
// Block = (chunk c, batch pair), 256 threads = 4 waves, 16 subtiles.
// Iter s: GEMM1(s+1) MFMA (from Us[nxt])  ||  scan(s) VALU (from Bu[cur]),
// then acc->Bu[nxt], stage U(s+2)->Us[cur], barrier. Invariants:
//   entering iter s: Bu[cur]=Bu(s) (filled iter s-1 + barrier),
//   Us[nxt]=U(s+1), uregs=U(s+2).
// Pass1: 1 barrier/subtile. Pass2: +bar2 after GEMM2 (Xs single-buffered).
// MFMA 16x16x32 bf16: A row=lane&15, k=(lane>>4)*8+j; C/D col=lane&15,
// row=(lane>>4)*4+i.
// NOTE: __launch_bounds__(256,2) — tighter bounds spill fragments (R4/R11).
// ---------------------------------------------------------------------------
template <bool FINAL>
__global__ __launch_bounds__(256, 2) void scan_mfma(
    const float* __restrict__ U,      // (NHRZ, BATCH, NU)
    const float* __restrict__ lre,    // (H,)
    const float* __restrict__ lim,    // (H,)
    const float* __restrict__ Bmat,   // (NH, NU)
    const float* __restrict__ Wx2y,   // (NY, NH)   [FINAL]
    const float* __restrict__ bx2y,   // (NY,)      [FINAL]
    const float* __restrict__ starts, // (NCHUNK, BATCH, NH) [FINAL]
    float* __restrict__ ends,         // (NCHUNK, BATCH, NH) [!FINAL]
    float* __restrict__ out)          // (NHRZ+1, BATCH, NY) [FINAL]
{
    extern __shared__ char smem[];
    __bf16* UsB = (__bf16*)(smem + OFF_U);    // [2][kM][U_STR]
    __bf16* BuB = (__bf16*)(smem + OFF_BU);   // [2][kM][BU_STR]
    __bf16* Xs  = (__bf16*)(smem + OFF_X);    // [kM][X_STR]  (FINAL)

    const int tid  = threadIdx.x;
    const int lane = tid & 63;
    const int w    = tid >> 6;            // wave 0..3
    const int lw   = lane & 15;
    const int lg   = lane >> 4;
    const int blk  = blockIdx.x;
    const int c    = blk >> 6;            // chunk 0..7
    const int bp   = blk & 63;            // batch pair 0..63
    const int bglob = bp * 2;
    const int t0   = c * kCHUNK;

    // --- B fragments in registers: wave w owns h-cols [w*64, w*64+64), nf folded
    bf16x8 Bf[2][4];  // [ks][nt]
#pragma unroll
    for (int nt = 0; nt < 4; ++nt) {
        const int h  = w * 64 + nt * 16 + lw;
        const float ab = fabsf(lre[h & (kH - 1)]);
        const float nf = sqrtf(fmaxf(0.0f, 1.0f - expf(-2.0f * ab)));
#pragma unroll
        for (int ks = 0; ks < 2; ++ks) {
            const float* p = Bmat + h * kNU + ks * 32 + lg * 8;
            float4 f0 = ((const float4*)p)[0];
            float4 f1 = ((const float4*)p)[1];
            f0.x *= nf; f0.y *= nf; f0.z *= nf; f0.w *= nf;
            f1.x *= nf; f1.y *= nf; f1.z *= nf; f1.w *= nf;
            Bf[ks][nt] = pack8(f0, f1);
        }
    }

    // --- W fragments + bias in registers (FINAL)
    bf16x8 Wf[8][2];
    float  bias[2] = {0.f, 0.f};
    if constexpr (FINAL) {
#pragma unroll
        for (int nt = 0; nt < 2; ++nt) {
            const int y = (w >> 1) * 32 + nt * 16 + lw;
            bias[nt] = bx2y[y];
#pragma unroll
            for (int ks = 0; ks < 8; ++ks) {
                const float* p = Wx2y + y * kNH + ks * 32 + lg * 8;
                Wf[ks][nt] = pack8(((const float4*)p)[0], ((const float4*)p)[1]);
            }
        }
    }

    // --- per-thread scan constants / state: thread = (hm, bl)
    const int hm = tid & 127;
    const int bl = tid >> 7;
    float lr, li;
    {
        const float ab = fabsf(lre[hm]);
        const float r  = expf(-ab);
        const float th = 1.5707963267948966f * lim[hm];
        lr = r * cosf(th);
        li = r * sinf(th);
    }
    float x1, x2;
    if constexpr (FINAL) {
        const size_t sb = ((size_t)c * kBATCH + bglob + bl) * kNH;
        x1 = starts[sb + hm];
        x2 = starts[sb + hm + kH];
    } else {
        x1 = 0.0f; x2 = 0.0f;
    }

    // U staging map: thread -> (m = tid>>3, q = tid&7), 32 B of U per thread
    const int sm = tid >> 3, sq = tid & 7;
    const float* uptr0 =
        U + ((size_t)(t0 + (sm >> 1)) * kBATCH + (bglob + (sm & 1))) * kNU + sq * 8;
    const size_t ustep = (size_t)kTS * kBATCH * kNU;

    // GEMM1 helper: A from given Us buffer, 16 MFMA into acc
    auto gemm1 = [&](const __bf16* Ubuf, f32x4 (&acc)[2][4]) {
#pragma unroll
        for (int ks = 0; ks < 2; ++ks) {
            bf16x8 a0 = *(const bf16x8*)&Ubuf[(lw)      * U_STR + ks * 32 + lg * 8];
            bf16x8 a1 = *(const bf16x8*)&Ubuf[(16 + lw) * U_STR + ks * 32 + lg * 8];
#pragma unroll
            for (int nt = 0; nt < 4; ++nt) {
                acc[0][nt] = __builtin_amdgcn_mfma_f32_16x16x32_bf16(a0, Bf[ks][nt], acc[0][nt], 0, 0, 0);
                acc[1][nt] = __builtin_amdgcn_mfma_f32_16x16x32_bf16(a1, Bf[ks][nt], acc[1][nt], 0, 0, 0);
            }
        }
    };
    auto store_bu = [&](__bf16* Bubuf, const f32x4 (&acc)[2][4]) {
#pragma unroll
        for (int mt = 0; mt < 2; ++mt)
#pragma unroll
            for (int nt = 0; nt < 4; ++nt)
#pragma unroll
                for (int i = 0; i < 4; ++i)
                    Bubuf[(mt * 16 + lg * 4 + i) * BU_STR + w * 64 + nt * 16 + lw] =
                        (__bf16)acc[mt][nt][i];
    };

    // --- prologue: fill Bu[0] (subtile 0), stage Us[1]=U(1), uregs=U(2)
    float4 u0 = ((const float4*)uptr0)[0];
    float4 u1 = ((const float4*)uptr0)[1];
    *(bf16x8*)&UsB[sm * U_STR + sq * 8] = pack8(u0, u1);   // Us[0] = U(0)
    u0 = ((const float4*)(uptr0 + ustep))[0];
    u1 = ((const float4*)(uptr0 + ustep))[1];
    __syncthreads();                                        // Us[0] visible
    {
        f32x4 acc[2][4] = {};
        gemm1(UsB, acc);
        store_bu(BuB, acc);                                 // Bu[0]
    }
    *(bf16x8*)&UsB[kM * U_STR + sm * U_STR + sq * 8] = pack8(u0, u1);  // Us[1]=U(1)
    if (2 < kNSUB) {
        u0 = ((const float4*)(uptr0 + 2 * ustep))[0];
        u1 = ((const float4*)(uptr0 + 2 * ustep))[1];
    }
    __syncthreads();                                        // Bu[0] + Us[1] visible

#pragma unroll 1
    for (int s = 0; s < kNSUB; ++s) {
        const int cur = s & 1, nxt = cur ^ 1;
        __bf16* Buc = BuB + cur * (kM * BU_STR);
        __bf16* Bun = BuB + nxt * (kM * BU_STR);
        __bf16* Usn = UsB + nxt * (kM * U_STR);
        __bf16* Usc = UsB + cur * (kM * U_STR);
        const bool hasNext = (s + 1 < kNSUB);

        // ---- GEMM1(s+1) on the matrix pipe (independent of scan(s))
        f32x4 acc[2][4] = {};
        if (hasNext) gemm1(Usn, acc);

        // ---- scan(s) on the VALU (reads Bu[cur], filled iter s-1 + barrier)
#pragma unroll
        for (int t = 0; t < kTS; ++t) {
            const int m = t * kBT + bl;
            const float bu1 = (float)Buc[m * BU_STR + hm];
            const float bu2 = (float)Buc[m * BU_STR + kH + hm];
            const float n1 = fmaf(lr, x1, fmaf(-li, x2, bu1));
            const float n2 = fmaf(li, x1, fmaf(lr, x2, bu2));
            x1 = n1; x2 = n2;
            if constexpr (FINAL) {
                Xs[m * X_STR + hm]      = (__bf16)x1;
                Xs[m * X_STR + kH + hm] = (__bf16)x2;
            }
        }

        // ---- commit Bu(s+1), stage U(s+2), prefetch U(s+3)
        if (hasNext) {
            store_bu(Bun, acc);
            if (s + 2 < kNSUB) {
                *(bf16x8*)&Usc[sm * U_STR + sq * 8] = pack8(u0, u1);
                if (s + 3 < kNSUB) {
                    u0 = ((const float4*)(uptr0 + (size_t)(s + 3) * ustep))[0];
                    u1 = ((const float4*)(uptr0 + (size_t)(s + 3) * ustep))[1];
                }
            }
        }

        if constexpr (FINAL) {
            __syncthreads();  // bar1: Xs(s) + Bu[nxt] + Us staged, visible
            // ---- GEMM2: M=32 (mt=w&1), N=32 (y base (w>>1)*32), K=256
            f32x4 acc2[2] = {};
            const int mt = w & 1;
#pragma unroll
            for (int ks = 0; ks < 8; ++ks) {
                bf16x8 a = *(const bf16x8*)&Xs[(mt * 16 + lw) * X_STR + ks * 32 + lg * 8];
                acc2[0] = __builtin_amdgcn_mfma_f32_16x16x32_bf16(a, Wf[ks][0], acc2[0], 0, 0, 0);
                acc2[1] = __builtin_amdgcn_mfma_f32_16x16x32_bf16(a, Wf[ks][1], acc2[1], 0, 0, 0);
            }
#pragma unroll
            for (int i = 0; i < 4; ++i) {
                const int m = mt * 16 + lg * 4 + i;
                const int t = t0 + s * kTS + (m >> 1);
                const int b = bglob + (m & 1);
                float* orow = out + ((size_t)(1 + t) * kBATCH + b) * kNY + (w >> 1) * 32 + lw;
#pragma unroll
                for (int nt = 0; nt < 2; ++nt)
                    orow[nt * 16] = acc2[nt][i] + bias[nt];
            }
            if (hasNext) __syncthreads();  // bar2: Xs reads done before overwrite
        } else {
            if (hasNext) __syncthreads();  // Bu[nxt] + Us staged, visible
        }
    }

    if constexpr (!FINAL) {
        const size_t eb = ((size_t)c * kBATCH + bglob + bl) * kNH;
        ends[eb + hm]      = x1;
        ends[eb + hm + kH] = x2;
    }
}

// ---------------------------------------------------------------------------
// Sequential combine over chunks + x0 computation. lambda^256 = 8 squarings.
// ---------------------------------------------------------------------------
__global__ __launch_bounds__(128) void combine_kernel(
    const float* __restrict__ y0, const float* __restrict__ Wy2x,
    const float* __restrict__ by2x, const float* __restrict__ lre,
    const float* __restrict__ lim, const float* __restrict__ ends,
    float* __restrict__ starts)
{
    const int b  = blockIdx.x;
    const int hm = threadIdx.x;

    const float ab = fabsf(lre[hm]);
    const float r  = expf(-ab);
    const float th = 1.5707963267948966f * lim[hm];
    float lr = r * cosf(th);
    float li = r * sinf(th);
    float pr = lr, pi = li;
#pragma unroll
    for (int k = 0; k < 8; ++k) {  // lambda^256 (kCHUNK = 256 = 2^8)
        const float nr = pr * pr - pi * pi;
        const float ni = 2.0f * pr * pi;
        pr = nr; pi = ni;
    }

    float s1 = by2x[hm];
    float s2 = by2x[hm + kH];
#pragma unroll 8
    for (int q = 0; q < kNY; ++q) {
        const float yv = y0[b * kNY + q];
        s1 = fmaf(Wy2x[hm * kNY + q], yv, s1);
        s2 = fmaf(Wy2x[(hm + kH) * kNY + q], yv, s2);
    }

    for (int c = 0; c < kNCHUNK; ++c) {
        const size_t base = ((size_t)c * kBATCH + b) * kNH;
        starts[base + hm]      = s1;
        starts[base + hm + kH] = s2;
        const float e1 = ends[base + hm];
        const float e2 = ends[base + hm + kH];
        const float n1 = fmaf(pr, s1, fmaf(-pi, s2, e1));
        const float n2 = fmaf(pi, s1, fmaf(pr, s2, e2));
        s1 = n1; s2 = n2;
    }
}

// Y row 0 = Wx2y @ x0 + bx2y  (x0 = starts[c=0])
__global__ __launch_bounds__(64) void y0_kernel(
    const float* __restrict__ starts, const float* __restrict__ Wx2y,
    const float* __restrict__ bx2y, float* __restrict__ out)
{
    const int b = blockIdx.x;
    const int y = threadIdx.x;
    const float* x0 = starts + (size_t)b * kNH;
    float acc = bx2y[y];
#pragma unroll 4
    for (int h = 0; h < kNH; h += 4) {
        float4 xv = *(const float4*)&x0[h];
        float4 wv = *(const float4*)&Wx2y[y * kNH + h];
        acc = fmaf(wv.x, xv.x, acc);
        acc = fmaf(wv.y, xv.y, acc);
        acc = fmaf(wv.z, xv.z, acc);
        acc = fmaf(wv.w, xv.w, acc);
    }
    out[(size_t)b * kNY + y] = acc;
}

extern "C" void kernel_launch(void* const* d_in, const int* in_sizes, int n_in,
                              void* d_out, int out_size, void* d_ws, size_t ws_size,
                              hipStream_t stream) {
    const float* y0   = (const float*)d_in[0];
    const float* U    = (const float*)d_in[1];
    const float* lre  = (const float*)d_in[2];
    const float* lim  = (const float*)d_in[3];
    const float* Bmat = (const float*)d_in[4];
    const float* Wy2x = (const float*)d_in[5];
    const float* by2x = (const float*)d_in[6];
    const float* Wx2y = (const float*)d_in[7];
    const float* bx2y = (const float*)d_in[8];
    float* out = (float*)d_out;

    float* ends   = (float*)d_ws;                          // 1 MB
    float* starts = ends + (size_t)kNCHUNK * kBATCH * kNH; // 1 MB

    const int grid = kNCHUNK * (kBATCH / kBT);  // 512 blocks

    scan_mfma<false><<<grid, 256, SMEM1, stream>>>(
        U, lre, lim, Bmat, nullptr, nullptr, nullptr, ends, nullptr);
    combine_kernel<<<kBATCH, 128, 0, stream>>>(
        y0, Wy2x, by2x, lre, lim, ends, starts);
    y0_kernel<<<kBATCH, 64, 0, stream>>>(starts, Wx2y, bx2y, out);
    scan_mfma<true><<<grid, 256, SMEM2, stream>>>(
        U, lre, lim, Bmat, Wx2y, bx2y, starts, nullptr, out);
}

// Round 14
// 76.887 us; speedup vs baseline: 1.2602x; 1.2602x over previous
//
#include <hip/hip_runtime.h>
#include <hip/hip_bf16.h>

typedef __bf16 bf16x8 __attribute__((ext_vector_type(8)));
typedef __bf16 bf16x4 __attribute__((ext_vector_type(4)));
typedef float  f32x4  __attribute__((ext_vector_type(4)));

constexpr int kNHRZ = 2048, kBATCH = 128, kNU = 64, kNY = 64, kNH = 256, kH = 128;
constexpr int kCHUNK = 256, kNCHUNK = kNHRZ / kCHUNK;  // 8 chunks of 256 steps
constexpr int kTS = 16, kBT = 2, kM = kTS * kBT;       // 32 (b,t) rows per subtile
constexpr int kNSUB = kCHUNK / kTS;                    // 16 subtiles per chunk

// LDS strides (elements)
constexpr int U_STR  = 72;   // bf16, 144 B rows
constexpr int BT_STR = 36;   // Bu_T[h][b*16+t], 72 B rows: b64-aligned; lane
                             // stride 18 dw -> <=4-way banks on b64 ops
constexpr int X_STR  = 264;  // bf16, 528 B rows (identity layout, scalar writes)

constexpr int OFF_U  = 0;                            // 32*72*2  = 4608 B
constexpr int OFF_BU = OFF_U + kM * U_STR * 2;       // Bu_T: 256*36*2 = 18432 B
constexpr int OFF_X  = OFF_BU + kNH * BT_STR * 2;    // 23040
constexpr int SMEM1  = OFF_X;                        // pass1: 23040 B
constexpr int SMEM2  = OFF_X + kM * X_STR * 2;       // pass2: 39936 B

__device__ inline bf16x8 pack8(float4 a, float4 b) {
    bf16x8 v;
    v[0] = (__bf16)a.x; v[1] = (__bf16)a.y; v[2] = (__bf16)a.z; v[3] = (__bf16)a.w;
    v[4] = (__bf16)b.x; v[5] = (__bf16)b.y; v[6] = (__bf16)b.z; v[7] = (__bf16)b.w;
    return v;
}

// ---------------------------------------------------------------------------
// Fused per-chunk kernel — R12 schedule (2-3 barriers/subtile), vector-LDS Bu.
// Block = (chunk c, batch pair), 256 threads = 4 waves, 16 subtiles.
// U staged b-major (row = b*16 + t): GEMM1 tile mt = batch, C/D rows = pure t.
// Bu stored TRANSPOSED: Bu_T[h][b*16+t] -> GEMM1 stores 8 x b64/lane (4
// contiguous t per acc quad); scan reads all 16 steps as 8 x b64 into regs.
// Scalar DS per wave/subtile: pass1 0 (was 64), pass2 32 (Xs only, was 96).
// MFMA 16x16x32 bf16: A row=lane&15, k=(lane>>4)*8+j; C/D col=lane&15,
// row=(lane>>4)*4+i.
// NOTE: __launch_bounds__(256,2) — tighter bounds spill fragments (R4/R11).
// ---------------------------------------------------------------------------
template <bool FINAL>
__global__ __launch_bounds__(256, 2) void scan_mfma(
    const float* __restrict__ U,      // (NHRZ, BATCH, NU)
    const float* __restrict__ lre,    // (H,)
    const float* __restrict__ lim,    // (H,)
    const float* __restrict__ Bmat,   // (NH, NU)
    const float* __restrict__ Wx2y,   // (NY, NH)   [FINAL]
    const float* __restrict__ bx2y,   // (NY,)      [FINAL]
    const float* __restrict__ starts, // (NCHUNK, BATCH, NH) [FINAL]
    float* __restrict__ ends,         // (NCHUNK, BATCH, NH) [!FINAL]
    float* __restrict__ out)          // (NHRZ+1, BATCH, NY) [FINAL]
{
    extern __shared__ char smem[];
    __bf16* Us  = (__bf16*)(smem + OFF_U);    // [kM][U_STR], rows b-major
    __bf16* BuT = (__bf16*)(smem + OFF_BU);   // [kNH][BT_STR]
    __bf16* Xs  = (__bf16*)(smem + OFF_X);    // [kM][X_STR]  (FINAL)

    const int tid  = threadIdx.x;
    const int lane = tid & 63;
    const int w    = tid >> 6;            // wave 0..3
    const int lw   = lane & 15;
    const int lg   = lane >> 4;
    const int blk  = blockIdx.x;
    const int c    = blk >> 6;            // chunk 0..7
    const int bp   = blk & 63;            // batch pair 0..63
    const int bglob = bp * 2;
    const int t0   = c * kCHUNK;

    // --- B fragments in registers: wave w owns h-cols [w*64, w*64+64), nf folded
    bf16x8 Bf[2][4];  // [ks][nt]
#pragma unroll
    for (int nt = 0; nt < 4; ++nt) {
        const int h  = w * 64 + nt * 16 + lw;
        const float ab = fabsf(lre[h & (kH - 1)]);
        const float nf = sqrtf(fmaxf(0.0f, 1.0f - expf(-2.0f * ab)));
#pragma unroll
        for (int ks = 0; ks < 2; ++ks) {
            const float* p = Bmat + h * kNU + ks * 32 + lg * 8;
            float4 f0 = ((const float4*)p)[0];
            float4 f1 = ((const float4*)p)[1];
            f0.x *= nf; f0.y *= nf; f0.z *= nf; f0.w *= nf;
            f1.x *= nf; f1.y *= nf; f1.z *= nf; f1.w *= nf;
            Bf[ks][nt] = pack8(f0, f1);
        }
    }

    // --- W fragments + bias in registers (FINAL)
    bf16x8 Wf[8][2];
    float  bias[2] = {0.f, 0.f};
    if constexpr (FINAL) {
#pragma unroll
        for (int nt = 0; nt < 2; ++nt) {
            const int y = (w >> 1) * 32 + nt * 16 + lw;
            bias[nt] = bx2y[y];
#pragma unroll
            for (int ks = 0; ks < 8; ++ks) {
                const float* p = Wx2y + y * kNH + ks * 32 + lg * 8;
                Wf[ks][nt] = pack8(((const float4*)p)[0], ((const float4*)p)[1]);
            }
        }
    }

    // --- per-thread scan constants / state: thread = (hm, bl)
    const int hm = tid & 127;
    const int bl = tid >> 7;
    float lr, li;
    {
        const float ab = fabsf(lre[hm]);
        const float r  = expf(-ab);
        const float th = 1.5707963267948966f * lim[hm];
        lr = r * cosf(th);
        li = r * sinf(th);
    }
    float x1, x2;
    if constexpr (FINAL) {
        const size_t sb = ((size_t)c * kBATCH + bglob + bl) * kNH;
        x1 = starts[sb + hm];
        x2 = starts[sb + hm + kH];
    } else {
        x1 = 0.0f; x2 = 0.0f;
    }

    // U staging map: thread -> (row sm = b*16 + t, q = tid&7), 32 B per thread
    const int sm = tid >> 3, sq = tid & 7;
    const int st_t = sm & 15, st_b = sm >> 4;
    const float* uptr0 =
        U + ((size_t)(t0 + st_t) * kBATCH + (bglob + st_b)) * kNU + sq * 8;

    // prefetch subtile 0
    float4 u0 = ((const float4*)uptr0)[0];
    float4 u1 = ((const float4*)uptr0)[1];

#pragma unroll 1
    for (int s = 0; s < kNSUB; ++s) {
        // ---- write staged U regs -> LDS, then issue next prefetch
        *(bf16x8*)&Us[sm * U_STR + sq * 8] = pack8(u0, u1);
        if (s + 1 < kNSUB) {
            const float* p = uptr0 + (size_t)(s + 1) * kTS * kBATCH * kNU;
            u0 = ((const float4*)p)[0];
            u1 = ((const float4*)p)[1];
        }
        __syncthreads();  // B: U staged (also: prev scan's BuT reads done)

        // ---- GEMM1: M=32 (2 batch tiles), N=256/4 waves, K=64 -> Bu_T
        {
            f32x4 acc[2][4] = {};
#pragma unroll
            for (int ks = 0; ks < 2; ++ks) {
                bf16x8 a0 = *(const bf16x8*)&Us[(lw)      * U_STR + ks * 32 + lg * 8];
                bf16x8 a1 = *(const bf16x8*)&Us[(16 + lw) * U_STR + ks * 32 + lg * 8];
#pragma unroll
                for (int nt = 0; nt < 4; ++nt) {
                    acc[0][nt] = __builtin_amdgcn_mfma_f32_16x16x32_bf16(a0, Bf[ks][nt], acc[0][nt], 0, 0, 0);
                    acc[1][nt] = __builtin_amdgcn_mfma_f32_16x16x32_bf16(a1, Bf[ks][nt], acc[1][nt], 0, 0, 0);
                }
            }
            // acc[mt][nt][i]: row t = lg*4+i (contiguous!), col h = w*64+nt*16+lw
#pragma unroll
            for (int mt = 0; mt < 2; ++mt)
#pragma unroll
                for (int nt = 0; nt < 4; ++nt) {
                    bf16x4 v;
                    v[0] = (__bf16)acc[mt][nt][0]; v[1] = (__bf16)acc[mt][nt][1];
                    v[2] = (__bf16)acc[mt][nt][2]; v[3] = (__bf16)acc[mt][nt][3];
                    *(bf16x4*)&BuT[(w * 64 + nt * 16 + lw) * BT_STR + mt * 16 + lg * 4] = v;
                }
        }
        __syncthreads();  // C: Bu_T ready (also: prev GEMM2's X reads done)

        // ---- scan, 16 steps from registers (8 x b64 vector loads)
        {
            bf16x4 qr[4], qi[4];
#pragma unroll
            for (int k = 0; k < 4; ++k) {
                qr[k] = *(const bf16x4*)&BuT[hm * BT_STR + bl * 16 + k * 4];
                qi[k] = *(const bf16x4*)&BuT[(hm + kH) * BT_STR + bl * 16 + k * 4];
            }
#pragma unroll
            for (int t = 0; t < kTS; ++t) {
                const float bu1 = (float)qr[t >> 2][t & 3];
                const float bu2 = (float)qi[t >> 2][t & 3];
                const float n1 = fmaf(lr, x1, fmaf(-li, x2, bu1));
                const float n2 = fmaf(li, x1, fmaf(lr, x2, bu2));
                x1 = n1; x2 = n2;
                if constexpr (FINAL) {
                    const int m = bl * 16 + t;   // b-major rows, match GEMM2
                    Xs[m * X_STR + hm]      = (__bf16)x1;
                    Xs[m * X_STR + kH + hm] = (__bf16)x2;
                }
            }
        }

        if constexpr (FINAL) {
            __syncthreads();  // D: X ready
            // ---- Y GEMM: batch tile mtY=w&1 (rows = pure t), N=32, K=256
            f32x4 acc2[2] = {};
            const int mtY = w & 1;
#pragma unroll
            for (int ks = 0; ks < 8; ++ks) {
                bf16x8 a = *(const bf16x8*)&Xs[(mtY * 16 + lw) * X_STR + ks * 32 + lg * 8];
                acc2[0] = __builtin_amdgcn_mfma_f32_16x16x32_bf16(a, Wf[ks][0], acc2[0], 0, 0, 0);
                acc2[1] = __builtin_amdgcn_mfma_f32_16x16x32_bf16(a, Wf[ks][1], acc2[1], 0, 0, 0);
            }
            // C/D row = t_local = lg*4+i; store 4 x 64B segments per instr
#pragma unroll
            for (int i = 0; i < 4; ++i) {
                const int t = t0 + s * kTS + lg * 4 + i;
                float* orow = out + ((size_t)(1 + t) * kBATCH + bglob + mtY) * kNY +
                              (w >> 1) * 32 + lw;
#pragma unroll
                for (int nt = 0; nt < 2; ++nt)
                    orow[nt * 16] = acc2[nt][i] + bias[nt];
            }
        }
    }

    if constexpr (!FINAL) {
        const size_t eb = ((size_t)c * kBATCH + bglob + bl) * kNH;
        ends[eb + hm]      = x1;
        ends[eb + hm + kH] = x2;
    }
}

// ---------------------------------------------------------------------------
// Sequential combine over chunks + x0 computation. lambda^256 = 8 squarings.
// ---------------------------------------------------------------------------
__global__ __launch_bounds__(128) void combine_kernel(
    const float* __restrict__ y0, const float* __restrict__ Wy2x,
    const float* __restrict__ by2x, const float* __restrict__ lre,
    const float* __restrict__ lim, const float* __restrict__ ends,
    float* __restrict__ starts)
{
    const int b  = blockIdx.x;
    const int hm = threadIdx.x;

    const float ab = fabsf(lre[hm]);
    const float r  = expf(-ab);
    const float th = 1.5707963267948966f * lim[hm];
    float lr = r * cosf(th);
    float li = r * sinf(th);
    float pr = lr, pi = li;
#pragma unroll
    for (int k = 0; k < 8; ++k) {  // lambda^256 (kCHUNK = 256 = 2^8)
        const float nr = pr * pr - pi * pi;
        const float ni = 2.0f * pr * pi;
        pr = nr; pi = ni;
    }

    float s1 = by2x[hm];
    float s2 = by2x[hm + kH];
#pragma unroll 8
    for (int q = 0; q < kNY; ++q) {
        const float yv = y0[b * kNY + q];
        s1 = fmaf(Wy2x[hm * kNY + q], yv, s1);
        s2 = fmaf(Wy2x[(hm + kH) * kNY + q], yv, s2);
    }

    for (int c = 0; c < kNCHUNK; ++c) {
        const size_t base = ((size_t)c * kBATCH + b) * kNH;
        starts[base + hm]      = s1;
        starts[base + hm + kH] = s2;
        const float e1 = ends[base + hm];
        const float e2 = ends[base + hm + kH];
        const float n1 = fmaf(pr, s1, fmaf(-pi, s2, e1));
        const float n2 = fmaf(pi, s1, fmaf(pr, s2, e2));
        s1 = n1; s2 = n2;
    }
}

// Y row 0 = Wx2y @ x0 + bx2y  (x0 = starts[c=0])
__global__ __launch_bounds__(64) void y0_kernel(
    const float* __restrict__ starts, const float* __restrict__ Wx2y,
    const float* __restrict__ bx2y, float* __restrict__ out)
{
    const int b = blockIdx.x;
    const int y = threadIdx.x;
    const float* x0 = starts + (size_t)b * kNH;
    float acc = bx2y[y];
#pragma unroll 4
    for (int h = 0; h < kNH; h += 4) {
        float4 xv = *(const float4*)&x0[h];
        float4 wv = *(const float4*)&Wx2y[y * kNH + h];
        acc = fmaf(wv.x, xv.x, acc);
        acc = fmaf(wv.y, xv.y, acc);
        acc = fmaf(wv.z, xv.z, acc);
        acc = fmaf(wv.w, xv.w, acc);
    }
    out[(size_t)b * kNY + y] = acc;
}

extern "C" void kernel_launch(void* const* d_in, const int* in_sizes, int n_in,
                              void* d_out, int out_size, void* d_ws, size_t ws_size,
                              hipStream_t stream) {
    const float* y0   = (const float*)d_in[0];
    const float* U    = (const float*)d_in[1];
    const float* lre  = (const float*)d_in[2];
    const float* lim  = (const float*)d_in[3];
    const float* Bmat = (const float*)d_in[4];
    const float* Wy2x = (const float*)d_in[5];
    const float* by2x = (const float*)d_in[6];
    const float* Wx2y = (const float*)d_in[7];
    const float* bx2y = (const float*)d_in[8];
    float* out = (float*)d_out;

    float* ends   = (float*)d_ws;                          // 1 MB
    float* starts = ends + (size_t)kNCHUNK * kBATCH * kNH; // 1 MB

    const int grid = kNCHUNK * (kBATCH / kBT);  // 512 blocks

    scan_mfma<false><<<grid, 256, SMEM1, stream>>>(
        U, lre, lim, Bmat, nullptr, nullptr, nullptr, ends, nullptr);
    combine_kernel<<<kBATCH, 128, 0, stream>>>(
        y0, Wy2x, by2x, lre, lim, ends, starts);
    y0_kernel<<<kBATCH, 64, 0, stream>>>(starts, Wx2y, bx2y, out);
    scan_mfma<true><<<grid, 256, SMEM2, stream>>>(
        U, lre, lim, Bmat, Wx2y, bx2y, starts, nullptr, out);
}